// Round 1
// baseline (11.286 us; speedup 1.0000x reference)
//
#include <hip/hip_runtime.h>

// ChannelSimLoss1D: mean_b [ (nnz(x_b) + nnz(y_b) - 2 * S_b * cos(x_b,y_b)) / C ]
// where S_b = sum_i sign(x_bi)*sign(y_bi), derived from the closed form of the
// row-normalized gram of an outer product (see analysis). B=32, C=2048, f32.

constexpr int B = 32;
constexpr int C = 2048;
constexpr int THREADS = 256;

__global__ __launch_bounds__(THREADS) void csl_stage1(const float* __restrict__ x,
                                                      const float* __restrict__ y,
                                                      float* __restrict__ ws) {
    const int b = blockIdx.x;
    const int tid = threadIdx.x;
    const float4* x4 = reinterpret_cast<const float4*>(x + (size_t)b * C);
    const float4* y4 = reinterpret_cast<const float4*>(y + (size_t)b * C);

    float sx2 = 0.f, sy2 = 0.f, sxy = 0.f, sp = 0.f, cx = 0.f, cy = 0.f;
    #pragma unroll
    for (int i = tid; i < C / 4; i += THREADS) {   // 2 float4 per thread
        const float4 a = x4[i];
        const float4 c4 = y4[i];
        const float av[4] = {a.x, a.y, a.z, a.w};
        const float bv[4] = {c4.x, c4.y, c4.z, c4.w};
        #pragma unroll
        for (int k = 0; k < 4; ++k) {
            const float u = av[k], v = bv[k];
            sx2 = fmaf(u, u, sx2);
            sy2 = fmaf(v, v, sy2);
            sxy = fmaf(u, v, sxy);
            const float su = (u > 0.f) ? 1.f : ((u < 0.f) ? -1.f : 0.f);
            const float sv = (v > 0.f) ? 1.f : ((v < 0.f) ? -1.f : 0.f);
            sp += su * sv;
            cx += (u != 0.f) ? 1.f : 0.f;   // nnz (sign(0)=0 handles EPS branch)
            cy += (v != 0.f) ? 1.f : 0.f;
        }
    }

    // wave64 shuffle reduce (6 values fused)
    #pragma unroll
    for (int off = 32; off >= 1; off >>= 1) {
        sx2 += __shfl_down(sx2, off);
        sy2 += __shfl_down(sy2, off);
        sxy += __shfl_down(sxy, off);
        sp  += __shfl_down(sp,  off);
        cx  += __shfl_down(cx,  off);
        cy  += __shfl_down(cy,  off);
    }

    __shared__ float red[6][THREADS / 64];
    const int wave = tid >> 6;
    if ((tid & 63) == 0) {
        red[0][wave] = sx2; red[1][wave] = sy2; red[2][wave] = sxy;
        red[3][wave] = sp;  red[4][wave] = cx;  red[5][wave] = cy;
    }
    __syncthreads();
    if (tid == 0) {
        float t[6];
        #pragma unroll
        for (int j = 0; j < 6; ++j) {
            t[j] = red[j][0];
            #pragma unroll
            for (int w = 1; w < THREADS / 64; ++w) t[j] += red[j][w];
        }
        const float nx = sqrtf(t[0]);
        const float ny = sqrtf(t[1]);
        const float denom = fmaxf(nx * ny, 1e-24f);
        const float cosv = t[2] / denom;
        // ||Ahat(x) - Ahat(y)||_F^2 = nnz_x + nnz_y - 2 * S * cos
        ws[b] = t[4] + t[5] - 2.f * t[3] * cosv;
    }
}

__global__ __launch_bounds__(64) void csl_stage2(const float* __restrict__ ws,
                                                 float* __restrict__ out) {
    const int tid = threadIdx.x;
    float v = (tid < B) ? ws[tid] : 0.f;
    #pragma unroll
    for (int off = 32; off >= 1; off >>= 1) v += __shfl_down(v, off);
    if (tid == 0) out[0] = v / (float)(B * C);
}

extern "C" void kernel_launch(void* const* d_in, const int* in_sizes, int n_in,
                              void* d_out, int out_size, void* d_ws, size_t ws_size,
                              hipStream_t stream) {
    const float* x = (const float*)d_in[0];
    const float* y = (const float*)d_in[1];
    float* ws = (float*)d_ws;   // 32 floats of scratch
    csl_stage1<<<B, THREADS, 0, stream>>>(x, y, ws);
    csl_stage2<<<1, 64, 0, stream>>>(ws, (float*)d_out);
}

// Round 2
// 9.557 us; speedup vs baseline: 1.1810x; 1.1810x over previous
//
#include <hip/hip_runtime.h>

// ChannelSimLoss1D, fused single-dispatch version.
// Closed form: per sample, ||rowNormGram(x) - rowNormGram(y)||_F^2
//   = nnz(x) + nnz(y) - 2 * (sum_i sign(x_i)sign(y_i)) * cos(x, y)
// Final: mean over B, divided by C.
// Cross-block finish via atomicInc(counter, 31): cycles mod 32, so exactly one
// block observes old==30 per call regardless of the counter's initial garbage
// (0xAA poison or stale value) -> deterministic under graph replay without
// any re-poisoning.

constexpr int B = 32;
constexpr int C = 2048;
constexpr int THREADS = 256;

__global__ __launch_bounds__(THREADS) void csl_fused(const float* __restrict__ x,
                                                     const float* __restrict__ y,
                                                     float* __restrict__ partials,
                                                     unsigned* __restrict__ counter,
                                                     float* __restrict__ out) {
    const int b = blockIdx.x;
    const int tid = threadIdx.x;
    const float4* x4 = reinterpret_cast<const float4*>(x + (size_t)b * C);
    const float4* y4 = reinterpret_cast<const float4*>(y + (size_t)b * C);

    float sx2 = 0.f, sy2 = 0.f, sxy = 0.f, sp = 0.f, cx = 0.f, cy = 0.f;
    #pragma unroll
    for (int i = tid; i < C / 4; i += THREADS) {   // 2 float4 per thread per array
        const float4 a = x4[i];
        const float4 c4 = y4[i];
        const float av[4] = {a.x, a.y, a.z, a.w};
        const float bv[4] = {c4.x, c4.y, c4.z, c4.w};
        #pragma unroll
        for (int k = 0; k < 4; ++k) {
            const float u = av[k], v = bv[k];
            sx2 = fmaf(u, u, sx2);
            sy2 = fmaf(v, v, sy2);
            sxy = fmaf(u, v, sxy);
            const float su = (u > 0.f) ? 1.f : ((u < 0.f) ? -1.f : 0.f);
            const float sv = (v > 0.f) ? 1.f : ((v < 0.f) ? -1.f : 0.f);
            sp += su * sv;
            cx += (u != 0.f) ? 1.f : 0.f;   // nnz (sign(0)=0 covers the EPS branch)
            cy += (v != 0.f) ? 1.f : 0.f;
        }
    }

    // fused 6-way wave64 shuffle reduce
    #pragma unroll
    for (int off = 32; off >= 1; off >>= 1) {
        sx2 += __shfl_down(sx2, off);
        sy2 += __shfl_down(sy2, off);
        sxy += __shfl_down(sxy, off);
        sp  += __shfl_down(sp,  off);
        cx  += __shfl_down(cx,  off);
        cy  += __shfl_down(cy,  off);
    }

    __shared__ float red[6][THREADS / 64];
    __shared__ bool amLast;
    const int wave = tid >> 6;
    if ((tid & 63) == 0) {
        red[0][wave] = sx2; red[1][wave] = sy2; red[2][wave] = sxy;
        red[3][wave] = sp;  red[4][wave] = cx;  red[5][wave] = cy;
    }
    __syncthreads();

    if (tid == 0) {
        float t[6];
        #pragma unroll
        for (int j = 0; j < 6; ++j) {
            t[j] = red[j][0];
            #pragma unroll
            for (int w = 1; w < THREADS / 64; ++w) t[j] += red[j][w];
        }
        const float nx = sqrtf(t[0]);
        const float ny = sqrtf(t[1]);
        const float denom = fmaxf(nx * ny, 1e-24f);
        const float cosv = t[2] / denom;
        const float val = t[4] + t[5] - 2.f * t[3] * cosv;

        // publish partial device-wide, then arrive
        __hip_atomic_store(&partials[b], val, __ATOMIC_RELAXED, __HIP_MEMORY_SCOPE_AGENT);
        __threadfence();
        const unsigned old = atomicInc(counter, 31u);   // cycles 0..31
        amLast = (old == 30u);                          // unique 32nd arriver
    }
    __syncthreads();

    if (amLast && tid < 64) {
        __threadfence();
        float v = (tid < B)
            ? __hip_atomic_load(&partials[tid], __ATOMIC_RELAXED, __HIP_MEMORY_SCOPE_AGENT)
            : 0.f;
        #pragma unroll
        for (int off = 32; off >= 1; off >>= 1) v += __shfl_down(v, off);
        if (tid == 0) out[0] = v / (float)(B * C);
    }
}

extern "C" void kernel_launch(void* const* d_in, const int* in_sizes, int n_in,
                              void* d_out, int out_size, void* d_ws, size_t ws_size,
                              hipStream_t stream) {
    const float* x = (const float*)d_in[0];
    const float* y = (const float*)d_in[1];
    float* partials = (float*)d_ws;                                  // 32 floats
    unsigned* counter = (unsigned*)((char*)d_ws + 256);              // own cache line
    csl_fused<<<B, THREADS, 0, stream>>>(x, y, partials, counter, (float*)d_out);
}